// Round 11
// baseline (159.532 us; speedup 1.0000x reference)
//
#include <hip/hip_runtime.h>
#include <math.h>

#define N 8192
#define D 256
#define EPSF 1e-8f
#define NJS 2            // j-splits
#define ROWS 32          // out-rows per block
#define JSPAN 4096       // j-cols per block
#define NCH 32           // 128-j chunks per block

// ws float offsets
#define WS_SQ    0
#define WS_RINV  (N)
#define WS_GMEAN (2*N)
#define WS_MAXN  (2*N+256)
#define WS_COLP  (2*N+512)              // [65536]
#define WS_P0    (2*N+512+65536)        // deg[2N] pot[2N] sl[2N] st[2N] keys[12N]
#define WS_EBF   (WS_P0+56*N)           // [2M ushort] bf16 emb (4MB)

typedef __attribute__((ext_vector_type(8))) short bf16x8;
typedef __attribute__((ext_vector_type(4))) float f32x4;

__device__ __forceinline__ unsigned short f2bf(float f) {
    unsigned u = __float_as_uint(f);
    u += 0x7fffu + ((u >> 16) & 1u);
    return (unsigned short)(u >> 16);
}

#if __has_builtin(__builtin_amdgcn_fmed3f)
#define MED3(a,b,c) __builtin_amdgcn_fmed3f((a),(b),(c))
#else
#define MED3(a,b,c) fmaxf(fminf((a),(b)), fminf(fmaxf((a),(b)),(c)))
#endif

// branchless sorted-6 insert on packed keys (val high 19 bits | index low 13).
// Slot 0 ends up = self (dp_self = -sq_r is the strict global min), mirroring
// the reference's top-(K+1)-drop-first.
#define PINS6(T, x) do {                                                        \
    float _x = (x);                                                             \
    float _n0 = fminf((T)[0], _x);                                              \
    float _n1 = MED3((T)[0], (T)[1], _x);                                       \
    float _n2 = MED3((T)[1], (T)[2], _x);                                       \
    float _n3 = MED3((T)[2], (T)[3], _x);                                       \
    float _n4 = MED3((T)[3], (T)[4], _x);                                       \
    float _n5 = MED3((T)[4], (T)[5], _x);                                       \
    (T)[0]=_n0; (T)[1]=_n1; (T)[2]=_n2; (T)[3]=_n3; (T)[4]=_n4; (T)[5]=_n5;     \
  } while (0)

__global__ void k_prep(const float* __restrict__ emb, float* __restrict__ ws,
                       unsigned short* __restrict__ ebf) {
    if (blockIdx.x < 2048) {
        int row = blockIdx.x * 4 + (threadIdx.x >> 6);
        int lane = threadIdx.x & 63;
        float4 v = *(const float4*)(emb + (size_t)row * D + lane * 4);
        ushort4 b;
        b.x = f2bf(v.x); b.y = f2bf(v.y); b.z = f2bf(v.z); b.w = f2bf(v.w);
        *(ushort4*)(ebf + (size_t)row * D + lane * 4) = b;
        float s = v.x * v.x + v.y * v.y + v.z * v.z + v.w * v.w;
#pragma unroll
        for (int mk = 32; mk >= 1; mk >>= 1) s += __shfl_xor(s, mk);
        if (lane == 0) {
            ws[WS_SQ + row] = s;
            ws[WS_RINV + row] = 1.0f / fmaxf(sqrtf(s), 1e-12f);
        }
    } else {
        int d = threadIdx.x;
        int b = blockIdx.x - 2048;
        float s = 0.f;
        for (int r = b * 32; r < b * 32 + 32; ++r) s += emb[(size_t)r * D + d];
        ws[WS_COLP + b * 256 + d] = s;
    }
}

__global__ void k_colred(float* __restrict__ ws) {
    __shared__ float red[256];
    int d = threadIdx.x;
    float s = 0.f;
    for (int b = 0; b < 256; ++b) s += ws[WS_COLP + b * 256 + d];
    ws[WS_GMEAN + d] = s * (1.0f / N);
    float mx = 0.f;
    for (int i = d; i < N; i += 256) mx = fmaxf(mx, ws[WS_SQ + i]);
    red[d] = mx;
    __syncthreads();
#pragma unroll
    for (int st2 = 128; st2 >= 1; st2 >>= 1) {
        if (d < st2) red[d] = fmaxf(red[d], red[d + st2]);
        __syncthreads();
    }
    if (d == 0) ws[WS_MAXN] = sqrtf(red[0]);
}

// Stage a [128 j][64 K] slab into buffer PTR (compile-time base). Wave w
// stages ONLY its own 32 rows (same rows it reads -> zero-barrier pipelines).
// SOFF: ushort offset affine in chunk (strength-reducible); K0 in {0,64,128,192}.
// Tail chunks stage garbage from within d_ws (never computed) -- no masking.
#define STAGE(PTR, SOFF, K0) do {                                               \
    _Pragma("unroll")                                                           \
    for (int q = 0; q < 4; ++q) {                                               \
      __builtin_amdgcn_global_load_lds(                                         \
        (const __attribute__((address_space(1))) void*)(ebf + gbase + (SOFF) + (K0) + q * (8 * D)), \
        (__attribute__((address_space(3))) void*)&(PTR)[((w << 5) + (q << 3)) * 64], \
        16, 0, 0);                                                              \
    } } while (0)

#define VMW(NLIT) do {                                                          \
    asm volatile("s_waitcnt vmcnt(" #NLIT ")" ::: "memory");                    \
    __builtin_amdgcn_sched_barrier(0);                                          \
  } while (0)

#define SBAR() __builtin_amdgcn_sched_barrier(0)

#define COMP(PTR, H) do {                                                       \
    _Pragma("unroll")                                                           \
    for (int ksl = 0; ksl < 2; ++ksl) {                                         \
      const int pg = ((ksl << 2) + g) ^ (lid & 7);                              \
      bf16x8 afr[2];                                                            \
      _Pragma("unroll")                                                         \
      for (int mf = 0; mf < 2; ++mf)                                            \
        afr[mf] = *(const bf16x8*)&(PTR)[((w << 5) + (mf << 4) + lid) * 64 + (pg << 3)]; \
      _Pragma("unroll")                                                         \
      for (int nf = 0; nf < 2; ++nf)                                            \
        _Pragma("unroll")                                                       \
        for (int mf = 0; mf < 2; ++mf)                                          \
          acc[nf][mf] = __builtin_amdgcn_mfma_f32_16x16x32_bf16(                \
              afr[mf], bfr[nf][(H) * 2 + ksl], acc[nf][mf], 0, 0, 0);           \
    } } while (0)

// Block = 32 out-rows x 4096 j; 4 waves share out-rows, each owns a 32-j
// quadrant per chunk. Zero-barrier private pipelines; FOUR fixed LDS buffers
// (unit u -> buffer u&3, no rotation: all LDS bases compile-time), counted
// vmcnt 16/20/16/8 (FIFO-traced; A window 3 phases, Q 2, stages 3-4).
__global__ __launch_bounds__(256) void k_main(
    const float* __restrict__ adj,
    const unsigned short* __restrict__ ebf,
    const float* __restrict__ ws,
    float* __restrict__ pout)
{
    __shared__ unsigned short tile0[128 * 64];   // 4 x 16KB, fixed mapping
    __shared__ unsigned short tile1[128 * 64];
    __shared__ unsigned short tile2[128 * 64];
    __shared__ unsigned short tile3[128 * 64];

    const int tid = threadIdx.x;
    const int w = tid >> 6;
    const int l = tid & 63;
    const int lid = l & 15;
    const int g = l >> 4;
    const int srow = l >> 3;
    const int sc = (l & 7) ^ srow;
    const int panel = blockIdx.x >> 1;    // 256 panels
    const int js = blockIdx.x & 1;
    const int row0 = panel * ROWS;
    const int j0 = js * JSPAN;

    const float* sq = ws + WS_SQ;
    const float* rinv = ws + WS_RINV;
    const size_t gbase = (size_t)(j0 + (w << 5) + srow) * D + (sc << 3);

    bf16x8 bfr[2][8];
    float rvr[2];
    int r_[2];
#pragma unroll
    for (int nf = 0; nf < 2; ++nf) {
        int r = row0 + nf * 16 + lid;
        r_[nf] = r;
        rvr[nf] = rinv[r];
#pragma unroll
        for (int ks = 0; ks < 8; ++ks)
            bfr[nf][ks] = *(const bf16x8*)(ebf + (size_t)r * D + ks * 32 + g * 8);
    }

    float deg[2] = {0.f, 0.f}, pot[2] = {0.f, 0.f};
    float sl[2] = {0.f, 0.f}, st[2] = {0.f, 0.f};
    float tv[2][6];
#pragma unroll
    for (int nf = 0; nf < 2; ++nf)
#pragma unroll
        for (int s2 = 0; s2 < 6; ++s2) tv[nf][s2] = 1e30f;

    f32x4 acc[2][2];
#pragma unroll
    for (int nf = 0; nf < 2; ++nf)
#pragma unroll
        for (int mf = 0; mf < 2; ++mf) acc[nf][mf] = (f32x4){0.f, 0.f, 0.f, 0.f};
    f32x4 advA[2][2], sqv[2], rvv[2];

    // prologue: stage units 0..3 into buffers 0..3 (16 outstanding)
    STAGE(tile0, 0, 0);
    STAGE(tile1, 0, 64);
    STAGE(tile2, 0, 128);
    STAGE(tile3, 0, 192);

#pragma unroll 1
    for (int cc = 0; cc < NCH; ++cc) {
        const int jj = j0 + cc * 128 + (w << 5);
        const size_t snext = (size_t)(cc + 1) * (128 * D);  // next chunk's slab

        // h0: adj issue (window h0->h3); wait S(u0); compute b0; restage b0
#pragma unroll
        for (int nf = 0; nf < 2; ++nf)
#pragma unroll
            for (int mf = 0; mf < 2; ++mf)
                advA[nf][mf] = __builtin_nontemporal_load(
                    (const f32x4*)(adj + (size_t)r_[nf] * N + jj + mf * 16 + g * 4));
        VMW(16);
        COMP(tile0, 0);
        SBAR();
        STAGE(tile0, snext, 0);

        // h1: j-stats issue (window h1->h3); wait S(u0+1); compute b1; restage
#pragma unroll
        for (int mf = 0; mf < 2; ++mf) {
            sqv[mf] = *(const f32x4*)(sq + jj + mf * 16 + g * 4);
            rvv[mf] = *(const f32x4*)(rinv + jj + mf * 16 + g * 4);
        }
        VMW(20);
        COMP(tile1, 1);
        SBAR();
        STAGE(tile1, snext, 64);

        // h2: wait S(u0+2) (+old S(u0+3)); compute b2; restage
        VMW(16);
        COMP(tile2, 2);
        SBAR();
        STAGE(tile2, snext, 128);

        // h3: drain A,Q (and S(u0+3),S(u0+4)); compute b3; restage; epilogue
        VMW(8);
        COMP(tile3, 3);
        SBAR();
        STAGE(tile3, snext, 192);
#pragma unroll
        for (int nf = 0; nf < 2; ++nf) {
#pragma unroll
            for (int mf = 0; mf < 2; ++mf) {
#pragma unroll
                for (int e = 0; e < 4; ++e) {
                    const float gv = acc[nf][mf][e];
                    const float a = advA[nf][mf][e];
                    const int j = jj + mf * 16 + g * 4 + e;
                    deg[nf] += a;
                    pot[nf] = fmaf(a, gv, pot[nf]);
                    const float s = (gv * rvr[nf]) * (rvv[mf][e] * a);
                    const float ex = __expf(s);
                    sl[nf] += ex;
                    st[nf] = fmaf(ex, s, st[nf]);
                    const float dp = fmaf(-2.f, gv, sqv[mf][e]);  // no self-mask
                    const float key = __uint_as_float(
                        (__float_as_uint(dp) & 0xFFFFE000u) | (unsigned)j);
                    PINS6(tv[nf], key);
                }
                acc[nf][mf] = (f32x4){0.f, 0.f, 0.f, 0.f};
            }
        }
    }

    // reduce across g-lanes (xor 16, 32) sharing each out-row
#pragma unroll
    for (int nf = 0; nf < 2; ++nf) {
#pragma unroll
        for (int mk = 16; mk <= 32; mk <<= 1) {
            deg[nf] += __shfl_xor(deg[nf], mk);
            pot[nf] += __shfl_xor(pot[nf], mk);
            sl[nf] += __shfl_xor(sl[nf], mk);
            st[nf] += __shfl_xor(st[nf], mk);
            float ok[6];
#pragma unroll
            for (int s2 = 0; s2 < 6; ++s2) ok[s2] = __shfl_xor(tv[nf][s2], mk);
#pragma unroll
            for (int s2 = 0; s2 < 6; ++s2) PINS6(tv[nf], ok[s2]);
        }
    }

    // cross-wave merge via LDS overlay on tile0 (syncthreads drains vmcnt ->
    // outstanding dummy stages complete before overlay writes)
    __syncthreads();
    float* lds_s = (float*)&tile0[0];              // [4][32][4]
    float* lds_k = lds_s + 4 * 32 * 4;             // [4][32][6]
#pragma unroll
    for (int nf = 0; nf < 2; ++nf) {
        if (g == 0) {
            int lr = nf * 16 + lid;
            lds_s[(w * 32 + lr) * 4 + 0] = deg[nf];
            lds_s[(w * 32 + lr) * 4 + 1] = pot[nf];
            lds_s[(w * 32 + lr) * 4 + 2] = sl[nf];
            lds_s[(w * 32 + lr) * 4 + 3] = st[nf];
#pragma unroll
            for (int s2 = 0; s2 < 6; ++s2)
                lds_k[(w * 32 + lr) * 6 + s2] = tv[nf][s2];
        }
    }
    __syncthreads();

    if (tid < 32) {
        float dg = 0.f, pt = 0.f, ll = 0.f, tt = 0.f;
#pragma unroll
        for (int w2 = 0; w2 < 4; ++w2) {
            dg += lds_s[(w2 * 32 + tid) * 4 + 0];
            pt += lds_s[(w2 * 32 + tid) * 4 + 1];
            ll += lds_s[(w2 * 32 + tid) * 4 + 2];
            tt += lds_s[(w2 * 32 + tid) * 4 + 3];
        }
        float mk6[6];
#pragma unroll
        for (int s2 = 0; s2 < 6; ++s2) mk6[s2] = lds_k[tid * 6 + s2];
#pragma unroll
        for (int w2 = 1; w2 < 4; ++w2)
#pragma unroll
            for (int s2 = 0; s2 < 6; ++s2)
                PINS6(mk6, lds_k[(w2 * 32 + tid) * 6 + s2]);
        const int slot = js * N + row0 + tid;
        pout[slot] = dg;
        pout[2 * N + slot] = pt;
        pout[4 * N + slot] = ll;
        pout[6 * N + slot] = tt;
#pragma unroll
        for (int s2 = 0; s2 < 6; ++s2)
            pout[8 * N + slot * 6 + s2] = mk6[s2];
    }
}

__global__ void k_final(const float* __restrict__ emb, const float* __restrict__ ws,
                        float* __restrict__ out) {
    int row = blockIdx.x * 4 + (threadIdx.x >> 6);
    int lane = threadIdx.x & 63;
    const float* p0 = ws + WS_P0;

    float dg = 0.f, pt = 0.f, ll = 0.f, tt = 0.f;
#pragma unroll
    for (int js = 0; js < NJS; ++js) {
        int slot = js * N + row;
        dg += p0[slot]; pt += p0[2 * N + slot];
        ll += p0[4 * N + slot]; tt += p0[6 * N + slot];
    }

    float keys[6];
#pragma unroll
    for (int s = 0; s < 6; ++s) keys[s] = p0[8 * N + (size_t)row * 6 + s];
#pragma unroll
    for (int s = 0; s < 6; ++s) PINS6(keys, p0[8 * N + (size_t)(N + row) * 6 + s]);
    // keys[0] = self (dp = -sq_r, strict min); neighbors are keys[1..5]
    int nb[5];
#pragma unroll
    for (int t = 0; t < 5; ++t) nb[t] = (int)(__float_as_uint(keys[t + 1]) & 0x1FFFu);

    float4 e = *(const float4*)(emb + (size_t)row * D + lane * 4);
    float4 gm = *(const float4*)(ws + WS_GMEAN + lane * 4);
    float gx = e.x - gm.x, gy = e.y - gm.y, gz = e.z - gm.z, gw = e.w - gm.w;
    float gd = gx * gx + gy * gy + gz * gz + gw * gw;
    float ax = 0.f, ay = 0.f, az = 0.f, aw = 0.f;
#pragma unroll
    for (int t = 0; t < 5; ++t) {
        float4 nv = *(const float4*)(emb + (size_t)nb[t] * D + lane * 4);
        ax += nv.x; ay += nv.y; az += nv.z; aw += nv.w;
    }
    ax *= 0.2f; ay *= 0.2f; az *= 0.2f; aw *= 0.2f;
    float lx = e.x - ax, ly = e.y - ay, lz = e.z - az, lw = e.w - aw;
    float ld = lx * lx + ly * ly + lz * lz + lw * lw;
#pragma unroll
    for (int mk = 32; mk >= 1; mk >>= 1) {
        gd += __shfl_xor(gd, mk);
        ld += __shfl_xor(ld, mk);
    }
    if (lane == 0) {
        float sqv = ws[WS_SQ + row];
        float mn = ws[WS_MAXN];
        float ent = logf(ll) - tt / ll;
        out[row] = sqv - pt / (dg + EPSF);
        out[N + row] = (dg > 0.f) ? ent : 0.f;
        out[2 * N + row] = 0.6f * sqrtf(gd) + 0.4f * sqrtf(ld);
        out[3 * N + row] = 0.5f * (dg / (8191.0f + EPSF)) + 0.5f * (sqrtf(sqv) / (mn + EPSF));
    }
}

extern "C" void kernel_launch(void* const* d_in, const int* in_sizes, int n_in,
                              void* d_out, int out_size, void* d_ws, size_t ws_size,
                              hipStream_t stream) {
    const float* emb = (const float*)d_in[0];
    const float* adj = (const float*)d_in[1];
    float* out = (float*)d_out;
    float* ws = (float*)d_ws;
    unsigned short* ebf = (unsigned short*)(ws + WS_EBF);

    k_prep<<<2304, 256, 0, stream>>>(emb, ws, ebf);
    k_colred<<<1, 256, 0, stream>>>(ws);
    k_main<<<512, 256, 0, stream>>>(adj, ebf, ws, ws + WS_P0);
    k_final<<<N / 4, 256, 0, stream>>>(emb, ws, out);
}